// Round 16
// baseline (91.340 us; speedup 1.0000x reference)
//
#include <hip/hip_runtime.h>
#include <hip/hip_bf16.h>
#include <stdint.h>

#define NPIX 512
#define NBC  96
#define NWG8 (NBC * 4)       // 384 blocks for s2g
#define NWG16 (NBC * 4)      // 384 blocks for s1x (2 mt x 2 nt per image)

typedef __attribute__((ext_vector_type(8))) short bf16x8;
typedef __attribute__((ext_vector_type(4))) float f32x4;
typedef __attribute__((ext_vector_type(8))) unsigned short u16x8;

__device__ __forceinline__ unsigned short f2bf(float f) {
    __hip_bfloat16 h = __float2bfloat16(f);
    union { __hip_bfloat16 h; unsigned short u; } v;
    v.h = h;
    return v.u;
}

#define GLD16(g, l) __builtin_amdgcn_global_load_lds( \
    (const __attribute__((address_space(1))) void*)(const void*)(g), \
    (__attribute__((address_space(3))) void*)(void*)(l), 16, 0, 0)

#define SBAR() do { __builtin_amdgcn_sched_barrier(0); \
                    __builtin_amdgcn_s_barrier(); \
                    __builtin_amdgcn_sched_barrier(0); } while (0)
#define LGKM0() do { asm volatile("s_waitcnt lgkmcnt(0)" ::: "memory"); \
                     __builtin_amdgcn_sched_barrier(0); } while (0)
#define SB0() __builtin_amdgcn_sched_barrier(0)
#define VMW(n) do { asm volatile("s_waitcnt vmcnt(" #n ")" ::: "memory"); } while (0)

// ---------------- D basis: D[k][n] = bf16(2*cos(pi*(2n+1)*k/1024)) ----------------
__global__ void k_basis(unsigned short* __restrict__ D) {
    int idx = blockIdx.x * 256 + threadIdx.x;
    int k = idx >> 9, n = idx & 511;
    int m = ((2 * n + 1) * k) & 2047;
    float ang = (float)m * 3.06796157577128218e-03f;  // pi/1024
    D[idx] = f2bf(2.0f * cosf(ang));
}

// ------------- Stage 1 v5: sT[l][h] = bf16( sum_n D[l][n]*X[h][n] ), fused fp32 staging -------------
// LDS-traffic-optimized: tile 256(l) x 256(h), 384 blocks (1.5 gen), wave C = 128x64, acc[8][4].
// Per-CU LDS traffic 10.5 -> 4.1 MB vs v4 (the measured bottleneck). BK=32, 16 single-barrier
// phases, 32-MFMA cluster. A bf16 2x16KB (1-phase lead, D L2-hot); B fp32 3x32KB (2-phase lead).
// FIFO: phase T issues [A(T+1)x2, B(T+2)x4]; steady wait vmcnt(4); T=15 vmcnt(0).
__global__ __launch_bounds__(512, 2) void k_s1x(
        const unsigned short* __restrict__ D,
        const float* __restrict__ X,
        unsigned short* __restrict__ sT) {
    __shared__ __align__(16) char LDS[131072];  // A: 2x16KB @0 | B: 3x32KB @32768

    const int bid = blockIdx.x;
    const int nb  = (bid & 7) * (NWG16 / 8) + (bid >> 3);
    const int bc = nb >> 2, mt = (nb >> 1) & 1, nt = nb & 1;
    const int mA0 = mt * 256, nB0 = nt * 256;   // mA0: D rows (l), nB0: X rows (h)
    const unsigned short* Aimg = D;
    const float* Bimg = X + (size_t)bc * NPIX * NPIX;

    const int tid  = threadIdx.x;
    const int lane = tid & 63;
    const int wid  = tid >> 6;
    const int wr = wid >> 2, wc = wid & 3;      // 2x4 wave grid; wave C = 128(l) x 64(h)
    const int rm = lane & 15;
    const int kq = lane >> 4;

    f32x4 acc[8][4] = {};
    bf16x8 aLo[4], aHi[4], b[4];

    // A tile: 256 rows x 32 bf16 (64B); 1024 chunks -> 2 GLD16/thread.
    auto stageA = [&](int kt, int p2) {
        #pragma unroll
        for (int it = 0; it < 2; ++it) {
            int c = it * 512 + tid;
            int rp = c >> 2, g = c & 3;
            int gs = g ^ ((rp >> 1) & 3);
            GLD16(Aimg + (size_t)(mA0 + rp) * NPIX + kt * 32 + gs * 8,
                  LDS + p2 * 16384 + c * 16);
        }
    };
    // B tile: 256 rows x 32 fp32 (128B); 2048 chunks -> 4 GLD16/thread.
    auto stageB = [&](int kt, int s3) {
        #pragma unroll
        for (int it = 0; it < 4; ++it) {
            int c = it * 512 + tid;
            int rp = c >> 3, g = c & 7;
            int gs = g ^ (rp & 7);
            GLD16(Bimg + (size_t)(nB0 + rp) * NPIX + kt * 32 + gs * 4,
                  LDS + 32768 + s3 * 32768 + c * 16);
        }
    };
    auto readA4 = [&](int p2, int half, bf16x8 (&a)[4]) {
        #pragma unroll
        for (int f = 0; f < 4; ++f) {
            int rp = wr * 128 + (half * 4 + f) * 16 + rm;
            int slot = kq ^ ((rp >> 1) & 3);
            a[f] = *(const bf16x8*)(LDS + p2 * 16384 + rp * 64 + slot * 16);
        }
    };
    auto readB = [&](int s3) {
        #pragma unroll
        for (int jj = 0; jj < 4; ++jj) {
            int rp = wc * 64 + jj * 16 + rm;
            const char* rb = LDS + 32768 + s3 * 32768 + rp * 128;
            f32x4 v0 = *(const f32x4*)(rb + (((kq * 2 + 0) ^ (rp & 7)) * 16));
            f32x4 v1 = *(const f32x4*)(rb + (((kq * 2 + 1) ^ (rp & 7)) * 16));
            bf16x8 t;
            t[0] = (short)f2bf(v0[0]); t[1] = (short)f2bf(v0[1]);
            t[2] = (short)f2bf(v0[2]); t[3] = (short)f2bf(v0[3]);
            t[4] = (short)f2bf(v1[0]); t[5] = (short)f2bf(v1[1]);
            t[6] = (short)f2bf(v1[2]); t[7] = (short)f2bf(v1[3]);
            b[jj] = t;
        }
    };

    // --- prologue (FIFO: B0 x4, A0 x2, B1 x4 -> entering T=0 wait vmcnt(4) retires B0+A0) ---
    stageB(0, 0); SB0();
    stageA(0, 0); SB0();
    stageB(1, 1); SB0();

    for (int T = 0; T < 16; ++T) {
        const int p2 = T & 1, p2n = p2 ^ 1;
        const int s3 = T % 3, s3b = (T + 2) % 3;
        if (T < 15) { VMW(4); } else { VMW(0); }
        SBAR();
        if (T + 1 < 16) { stageA(T + 1, p2n); SB0(); }
        if (T + 2 < 16) { stageB(T + 2, s3b); SB0(); }
        readB(s3);
        readA4(p2, 0, aLo);
        LGKM0();
        __builtin_amdgcn_s_setprio(1);
        #pragma unroll
        for (int f = 0; f < 4; ++f)
            #pragma unroll
            for (int jj = 0; jj < 4; ++jj)
                acc[f][jj] = __builtin_amdgcn_mfma_f32_16x16x32_bf16(
                    aLo[f], b[jj], acc[f][jj], 0, 0, 0);
        __builtin_amdgcn_s_setprio(0);
        readA4(p2, 1, aHi);
        LGKM0();
        __builtin_amdgcn_s_setprio(1);
        #pragma unroll
        for (int f = 0; f < 4; ++f)
            #pragma unroll
            for (int jj = 0; jj < 4; ++jj)
                acc[4 + f][jj] = __builtin_amdgcn_mfma_f32_16x16x32_bf16(
                    aHi[f], b[jj], acc[4 + f][jj], 0, 0, 0);
        __builtin_amdgcn_s_setprio(0);
    }

    // Direct bf16 epilogue: C[l][h] row-major IS sT.
    unsigned short* Co = sT + (size_t)bc * NPIX * NPIX;
    #pragma unroll
    for (int f8 = 0; f8 < 8; ++f8) {
        int l_ = mA0 + wr * 128 + f8 * 16 + kq * 4;
        #pragma unroll
        for (int jj = 0; jj < 4; ++jj) {
            int h_ = nB0 + wc * 64 + jj * 16 + rm;
            f32x4 v = acc[f8][jj];
            #pragma unroll
            for (int r = 0; r < 4; ++r)
                Co[(size_t)(l_ + r) * NPIX + h_] = f2bf(v[r]);
        }
    }
}

// ------------- Stage 2: out[k][l] = (D @ sT^T)[k][l] * 1e-3 (proven roofline, unchanged) -------------
__global__ __launch_bounds__(512) void k_s2g(
        const unsigned short* __restrict__ D,
        const unsigned short* __restrict__ sT,
        float* __restrict__ Cv) {
    __shared__ __align__(16) char LDS[131072];

    const int bid = blockIdx.x;
    const int nb  = (bid & 7) * (NWG8 / 8) + (bid >> 3);
    const int bc = nb >> 2, mt = (nb >> 1) & 1, nt = nb & 1;
    const int mA0 = mt * 256, nB0 = nt * 256;
    const unsigned short* Aimg = D;
    const unsigned short* Bimg = sT + (size_t)bc * NPIX * NPIX;

    const int tid  = threadIdx.x;
    const int lane = tid & 63;
    const int wid  = tid >> 6;
    const int wr = wid >> 2, wc = wid & 3;
    const int rm = lane & 15;
    const int kq = lane >> 4;

    f32x4 acc[8][4] = {};
    bf16x8 a[4][2], b0[2][2], b1[2][2];

    auto stageA = [&](int kt, int p, int H) {
        char* dst = LDS + p * 32768 + H * 16384;
        #pragma unroll
        for (int it = 0; it < 2; ++it) {
            int c = it * 512 + tid;
            int rp = c >> 3, g = c & 7;
            int gs = g ^ (rp & 7);
            int row = ((rp >> 6) << 7) + H * 64 + (rp & 63);
            GLD16(Aimg + (size_t)(mA0 + row) * NPIX + kt * 64 + gs * 8, dst + c * 16);
        }
    };
    auto stageB = [&](int kt, int p, int H) {
        char* dst = LDS + 65536 + p * 32768 + H * 16384;
        #pragma unroll
        for (int it = 0; it < 2; ++it) {
            int c = it * 512 + tid;
            int rp = c >> 3, g = c & 7;
            int gs = g ^ (rp & 7);
            int row = ((rp >> 5) << 6) + H * 32 + (rp & 31);
            GLD16(Bimg + (size_t)(nB0 + row) * NPIX + kt * 64 + gs * 8, dst + c * 16);
        }
    };
    auto readA = [&](int p, int mh) {
        const char* base = LDS + p * 32768 + mh * 16384;
        #pragma unroll
        for (int f = 0; f < 4; ++f) {
            int rp = wr * 64 + f * 16 + rm;
            #pragma unroll
            for (int ks = 0; ks < 2; ++ks) {
                int slot = (ks * 4 + kq) ^ (rm & 7);
                a[f][ks] = *(const bf16x8*)(base + rp * 128 + slot * 16);
            }
        }
    };
    auto readB = [&](int p, int nh, bf16x8 (&b)[2][2]) {
        const char* base = LDS + 65536 + p * 32768 + nh * 16384;
        #pragma unroll
        for (int jj = 0; jj < 2; ++jj) {
            int rp = wc * 32 + jj * 16 + rm;
            #pragma unroll
            for (int ks = 0; ks < 2; ++ks) {
                int slot = (ks * 4 + kq) ^ (rm & 7);
                b[jj][ks] = *(const bf16x8*)(base + rp * 128 + slot * 16);
            }
        }
    };
    auto mma = [&](int mh, int nh, bf16x8 (&b)[2][2]) {
        __builtin_amdgcn_s_setprio(1);
        #pragma unroll
        for (int f = 0; f < 4; ++f)
            #pragma unroll
            for (int jj = 0; jj < 2; ++jj)
                #pragma unroll
                for (int ks = 0; ks < 2; ++ks)
                    acc[mh * 4 + f][nh * 2 + jj] = __builtin_amdgcn_mfma_f32_16x16x32_bf16(
                        a[f][ks], b[jj][ks], acc[mh * 4 + f][nh * 2 + jj], 0, 0, 0);
        __builtin_amdgcn_s_setprio(0);
    };

    stageA(0, 0, 0); stageB(0, 0, 0); stageB(0, 0, 1); stageA(0, 0, 1);

    for (int T = 0; T < 7; ++T) {
        const int p = T & 1, pn = p ^ 1;
        asm volatile("s_waitcnt vmcnt(4)" ::: "memory"); SBAR();
        readA(p, 0); readB(p, 0, b0); stageA(T + 1, pn, 0);
        LGKM0(); mma(0, 0, b0);
        asm volatile("s_waitcnt vmcnt(4)" ::: "memory"); SBAR();
        readB(p, 1, b1); stageB(T + 1, pn, 0);
        LGKM0(); mma(0, 1, b1);
        asm volatile("s_waitcnt vmcnt(4)" ::: "memory"); SBAR();
        readA(p, 1); stageB(T + 1, pn, 1);
        LGKM0(); mma(1, 0, b0);
        SBAR();
        stageA(T + 1, pn, 1);
        mma(1, 1, b1);
    }
    {
        asm volatile("s_waitcnt vmcnt(4)" ::: "memory"); SBAR();
        readA(1, 0); readB(1, 0, b0); LGKM0(); mma(0, 0, b0);
        asm volatile("s_waitcnt vmcnt(2)" ::: "memory"); SBAR();
        readB(1, 1, b1); LGKM0(); mma(0, 1, b1);
        asm volatile("s_waitcnt vmcnt(0)" ::: "memory"); SBAR();
        readA(1, 1); LGKM0(); mma(1, 0, b0);
        SBAR();
        mma(1, 1, b1);
    }

    float* Co = Cv + (size_t)bc * NPIX * NPIX;
    #pragma unroll
    for (int mh = 0; mh < 2; ++mh)
        #pragma unroll
        for (int f = 0; f < 4; ++f) {
            int k_ = mA0 + wr * 128 + mh * 64 + f * 16 + kq * 4;
            #pragma unroll
            for (int nh = 0; nh < 2; ++nh)
                #pragma unroll
                for (int jj = 0; jj < 2; ++jj) {
                    int l_ = nB0 + wc * 64 + (nh * 2 + jj) * 16 + rm;
                    f32x4 v = acc[mh * 4 + f][nh * 2 + jj];
                    #pragma unroll
                    for (int r = 0; r < 4; ++r)
                        Co[(size_t)(k_ + r) * NPIX + l_] = v[r] * 1.0e-3f;
                }
        }
}

extern "C" void kernel_launch(void* const* d_in, const int* in_sizes, int n_in,
                              void* d_out, int out_size, void* d_ws, size_t ws_size,
                              hipStream_t stream) {
    const float* img = (const float*)d_in[0];
    float* out = (float*)d_out;

    unsigned short* D  = (unsigned short*)d_ws;                       // 512 KB
    unsigned short* sT = (unsigned short*)((char*)d_ws + 512 * 1024); // 48 MB

    k_basis<<<dim3(512 * 512 / 256), dim3(256), 0, stream>>>(D);

    // Stage 1 v5 (256x256 tile, LDS-traffic-minimized): sT[l][h]
    k_s1x<<<dim3(NWG16), dim3(512), 0, stream>>>(D, img, sT);

    // Stage 2: out[k][l] = (D @ sT^T)[k][l] * 1e-3
    k_s2g<<<dim3(NWG8), dim3(512), 0, stream>>>(D, sT, out);
}

// Round 17
// 85.587 us; speedup vs baseline: 1.0672x; 1.0672x over previous
//
#include <hip/hip_runtime.h>
#include <hip/hip_bf16.h>
#include <stdint.h>

#define NPIX 512
#define NBC  96
#define NWG8 (NBC * 4)       // 384 blocks for s2g
#define NWG13 (NBC * 8)      // 768 blocks for s1x (2 mt x 4 nt per image)

typedef __attribute__((ext_vector_type(8))) short bf16x8;
typedef __attribute__((ext_vector_type(4))) float f32x4;
typedef __attribute__((ext_vector_type(8))) unsigned short u16x8;

__device__ __forceinline__ unsigned short f2bf(float f) {
    __hip_bfloat16 h = __float2bfloat16(f);
    union { __hip_bfloat16 h; unsigned short u; } v;
    v.h = h;
    return v.u;
}

#define GLD16(g, l) __builtin_amdgcn_global_load_lds( \
    (const __attribute__((address_space(1))) void*)(const void*)(g), \
    (__attribute__((address_space(3))) void*)(void*)(l), 16, 0, 0)

#define SBAR() do { __builtin_amdgcn_sched_barrier(0); \
                    __builtin_amdgcn_s_barrier(); \
                    __builtin_amdgcn_sched_barrier(0); } while (0)
#define LGKM0() do { asm volatile("s_waitcnt lgkmcnt(0)" ::: "memory"); \
                     __builtin_amdgcn_sched_barrier(0); } while (0)
#define SB0() __builtin_amdgcn_sched_barrier(0)
#define VMW(n) do { asm volatile("s_waitcnt vmcnt(" #n ")" ::: "memory"); } while (0)

// ---------------- D basis: D[k][n] = bf16(2*cos(pi*(2n+1)*k/1024)) ----------------
__global__ void k_basis(unsigned short* __restrict__ D) {
    int idx = blockIdx.x * 256 + threadIdx.x;
    int k = idx >> 9, n = idx & 511;
    int m = ((2 * n + 1) * k) & 2047;
    float ang = (float)m * 3.06796157577128218e-03f;  // pi/1024
    D[idx] = f2bf(2.0f * cosf(ang));
}

// ------------- Stage 1 (R14-best): sT[l][h] = bf16( sum_n D[l][n]*X[h][n] ), fused fp32 staging -------------
// Tile 256(l) x 128(h), BK=32, 16 single-barrier phases, 16 MFMA/phase.
// 8 waves (2Mx4N), wave C = 128x32. LDS 80KB (A bf16 2x16KB, B fp32 3x16KB) -> 2 blocks/CU.
// FIFO ledger: phase T issues [A(T+1)x2, B(T+2)x2]; steady wait vmcnt(2); tail vmcnt(0).
// NOTE: dur ~60us is the d_in-read bandwidth wall (~1.8 TB/s for this buffer) — five schedule
// variants (R12-R16) all pinned here; do not re-attempt schedule changes.
__global__ __launch_bounds__(512, 4) void k_s1x(
        const unsigned short* __restrict__ D,
        const float* __restrict__ X,
        unsigned short* __restrict__ sT) {
    __shared__ __align__(16) char LDS[81920];   // A: 2x16KB @0 | B: 3x16KB @32768

    const int bid = blockIdx.x;
    const int nb  = (bid & 7) * (NWG13 / 8) + (bid >> 3);
    const int bc = nb >> 3, mt = (nb >> 2) & 1, nt = nb & 3;
    const int mA0 = mt * 256, nB0 = nt * 128;   // mA0: D rows (l), nB0: X rows (h)
    const unsigned short* Aimg = D;
    const float* Bimg = X + (size_t)bc * NPIX * NPIX;

    const int tid  = threadIdx.x;
    const int lane = tid & 63;
    const int wid  = tid >> 6;
    const int wr = wid >> 2, wc = wid & 3;      // 2x4 wave grid; wave C = 128x32
    const int rm = lane & 15;
    const int kq = lane >> 4;

    f32x4 acc[8][2] = {};
    bf16x8 a[4], b[2];

    // A FULL tile: 256 storage-rows x 32 bf16 (64B); 1024 chunks -> 2 GLD16/thread.
    auto stageA = [&](int kt, int p2) {
        #pragma unroll
        for (int it = 0; it < 2; ++it) {
            int c = it * 512 + tid;
            int rp = c >> 2, g = c & 3;
            int gs = g ^ ((rp >> 1) & 3);
            int row = ((rp >> 7) << 7) + ((rp >> 6) & 1) * 64 + (rp & 63);  // = rp
            GLD16(Aimg + (size_t)(mA0 + row) * NPIX + kt * 32 + gs * 8,
                  LDS + p2 * 16384 + c * 16);
        }
    };
    // B FULL tile: 128 storage-rows x 32 fp32 (128B); 1024 chunks -> 2 GLD16/thread.
    auto stageB = [&](int kt, int s3) {
        #pragma unroll
        for (int it = 0; it < 2; ++it) {
            int c = it * 512 + tid;
            int rp = c >> 3, g = c & 7;
            int gs = g ^ (rp & 7);
            GLD16(Bimg + (size_t)(nB0 + rp) * NPIX + kt * 32 + gs * 4,
                  LDS + 32768 + s3 * 16384 + c * 16);
        }
    };
    auto readA = [&](int p2, int mh) {
        #pragma unroll
        for (int f = 0; f < 4; ++f) {
            int rp = mh * 128 + wr * 64 + f * 16 + rm;   // storage row within the tile
            int slot = kq ^ ((rp >> 1) & 3);
            a[f] = *(const bf16x8*)(LDS + p2 * 16384 + rp * 64 + slot * 16);
        }
    };
    auto readB = [&](int s3) {
        #pragma unroll
        for (int jj = 0; jj < 2; ++jj) {
            int rp = wc * 32 + jj * 16 + rm;
            const char* rb = LDS + 32768 + s3 * 16384 + rp * 128;
            f32x4 v0 = *(const f32x4*)(rb + (((kq * 2 + 0) ^ (rp & 7)) * 16));
            f32x4 v1 = *(const f32x4*)(rb + (((kq * 2 + 1) ^ (rp & 7)) * 16));
            bf16x8 t;
            t[0] = (short)f2bf(v0[0]); t[1] = (short)f2bf(v0[1]);
            t[2] = (short)f2bf(v0[2]); t[3] = (short)f2bf(v0[3]);
            t[4] = (short)f2bf(v1[0]); t[5] = (short)f2bf(v1[1]);
            t[6] = (short)f2bf(v1[2]); t[7] = (short)f2bf(v1[3]);
            b[jj] = t;
        }
    };
    auto mma = [&](int mh) {
        __builtin_amdgcn_s_setprio(1);
        #pragma unroll
        for (int f = 0; f < 4; ++f)
            #pragma unroll
            for (int jj = 0; jj < 2; ++jj)
                acc[mh * 4 + f][jj] = __builtin_amdgcn_mfma_f32_16x16x32_bf16(
                    a[f], b[jj], acc[mh * 4 + f][jj], 0, 0, 0);
        __builtin_amdgcn_s_setprio(0);
    };

    // --- prologue (FIFO: B0, A0, B1 -> entering T=0 outstanding matches steady) ---
    stageB(0, 0); SB0();
    stageA(0, 0); SB0();
    stageB(1, 1); SB0();

    for (int T = 0; T < 16; ++T) {
        const int p2 = T & 1, p2n = p2 ^ 1;
        const int s3 = T % 3, s3b = (T + 2) % 3;
        if (T < 15) { VMW(2); } else { VMW(0); }
        SBAR();
        if (T + 1 < 16) { stageA(T + 1, p2n); SB0(); }
        if (T + 2 < 16) { stageB(T + 2, s3b); SB0(); }
        readB(s3);
        readA(p2, 0);
        LGKM0(); mma(0);
        readA(p2, 1);
        LGKM0(); mma(1);
    }

    // Direct bf16 epilogue: C[l][h] row-major IS sT.
    unsigned short* Co = sT + (size_t)bc * NPIX * NPIX;
    #pragma unroll
    for (int mh = 0; mh < 2; ++mh)
        #pragma unroll
        for (int f = 0; f < 4; ++f) {
            int l_ = mA0 + mh * 128 + wr * 64 + f * 16 + kq * 4;
            #pragma unroll
            for (int jj = 0; jj < 2; ++jj) {
                int h_ = nB0 + wc * 32 + jj * 16 + rm;
                f32x4 v = acc[mh * 4 + f][jj];
                #pragma unroll
                for (int r = 0; r < 4; ++r)
                    Co[(size_t)(l_ + r) * NPIX + h_] = f2bf(v[r]);
            }
        }
}

// ------------- Stage 2: out[k][l] = (D @ sT^T)[k][l] * 1e-3 (proven roofline: 148MB @ ~7TB/s) -------------
__global__ __launch_bounds__(512) void k_s2g(
        const unsigned short* __restrict__ D,
        const unsigned short* __restrict__ sT,
        float* __restrict__ Cv) {
    __shared__ __align__(16) char LDS[131072];

    const int bid = blockIdx.x;
    const int nb  = (bid & 7) * (NWG8 / 8) + (bid >> 3);
    const int bc = nb >> 2, mt = (nb >> 1) & 1, nt = nb & 1;
    const int mA0 = mt * 256, nB0 = nt * 256;
    const unsigned short* Aimg = D;
    const unsigned short* Bimg = sT + (size_t)bc * NPIX * NPIX;

    const int tid  = threadIdx.x;
    const int lane = tid & 63;
    const int wid  = tid >> 6;
    const int wr = wid >> 2, wc = wid & 3;
    const int rm = lane & 15;
    const int kq = lane >> 4;

    f32x4 acc[8][4] = {};
    bf16x8 a[4][2], b0[2][2], b1[2][2];

    auto stageA = [&](int kt, int p, int H) {
        char* dst = LDS + p * 32768 + H * 16384;
        #pragma unroll
        for (int it = 0; it < 2; ++it) {
            int c = it * 512 + tid;
            int rp = c >> 3, g = c & 7;
            int gs = g ^ (rp & 7);
            int row = ((rp >> 6) << 7) + H * 64 + (rp & 63);
            GLD16(Aimg + (size_t)(mA0 + row) * NPIX + kt * 64 + gs * 8, dst + c * 16);
        }
    };
    auto stageB = [&](int kt, int p, int H) {
        char* dst = LDS + 65536 + p * 32768 + H * 16384;
        #pragma unroll
        for (int it = 0; it < 2; ++it) {
            int c = it * 512 + tid;
            int rp = c >> 3, g = c & 7;
            int gs = g ^ (rp & 7);
            int row = ((rp >> 5) << 6) + H * 32 + (rp & 31);
            GLD16(Bimg + (size_t)(nB0 + row) * NPIX + kt * 64 + gs * 8, dst + c * 16);
        }
    };
    auto readA = [&](int p, int mh) {
        const char* base = LDS + p * 32768 + mh * 16384;
        #pragma unroll
        for (int f = 0; f < 4; ++f) {
            int rp = wr * 64 + f * 16 + rm;
            #pragma unroll
            for (int ks = 0; ks < 2; ++ks) {
                int slot = (ks * 4 + kq) ^ (rm & 7);
                a[f][ks] = *(const bf16x8*)(base + rp * 128 + slot * 16);
            }
        }
    };
    auto readB = [&](int p, int nh, bf16x8 (&b)[2][2]) {
        const char* base = LDS + 65536 + p * 32768 + nh * 16384;
        #pragma unroll
        for (int jj = 0; jj < 2; ++jj) {
            int rp = wc * 32 + jj * 16 + rm;
            #pragma unroll
            for (int ks = 0; ks < 2; ++ks) {
                int slot = (ks * 4 + kq) ^ (rm & 7);
                b[jj][ks] = *(const bf16x8*)(base + rp * 128 + slot * 16);
            }
        }
    };
    auto mma = [&](int mh, int nh, bf16x8 (&b)[2][2]) {
        __builtin_amdgcn_s_setprio(1);
        #pragma unroll
        for (int f = 0; f < 4; ++f)
            #pragma unroll
            for (int jj = 0; jj < 2; ++jj)
                #pragma unroll
                for (int ks = 0; ks < 2; ++ks)
                    acc[mh * 4 + f][nh * 2 + jj] = __builtin_amdgcn_mfma_f32_16x16x32_bf16(
                        a[f][ks], b[jj][ks], acc[mh * 4 + f][nh * 2 + jj], 0, 0, 0);
        __builtin_amdgcn_s_setprio(0);
    };

    stageA(0, 0, 0); stageB(0, 0, 0); stageB(0, 0, 1); stageA(0, 0, 1);

    for (int T = 0; T < 7; ++T) {
        const int p = T & 1, pn = p ^ 1;
        asm volatile("s_waitcnt vmcnt(4)" ::: "memory"); SBAR();
        readA(p, 0); readB(p, 0, b0); stageA(T + 1, pn, 0);
        LGKM0(); mma(0, 0, b0);
        asm volatile("s_waitcnt vmcnt(4)" ::: "memory"); SBAR();
        readB(p, 1, b1); stageB(T + 1, pn, 0);
        LGKM0(); mma(0, 1, b1);
        asm volatile("s_waitcnt vmcnt(4)" ::: "memory"); SBAR();
        readA(p, 1); stageB(T + 1, pn, 1);
        LGKM0(); mma(1, 0, b0);
        SBAR();
        stageA(T + 1, pn, 1);
        mma(1, 1, b1);
    }
    {
        asm volatile("s_waitcnt vmcnt(4)" ::: "memory"); SBAR();
        readA(1, 0); readB(1, 0, b0); LGKM0(); mma(0, 0, b0);
        asm volatile("s_waitcnt vmcnt(2)" ::: "memory"); SBAR();
        readB(1, 1, b1); LGKM0(); mma(0, 1, b1);
        asm volatile("s_waitcnt vmcnt(0)" ::: "memory"); SBAR();
        readA(1, 1); LGKM0(); mma(1, 0, b0);
        SBAR();
        mma(1, 1, b1);
    }

    float* Co = Cv + (size_t)bc * NPIX * NPIX;
    #pragma unroll
    for (int mh = 0; mh < 2; ++mh)
        #pragma unroll
        for (int f = 0; f < 4; ++f) {
            int k_ = mA0 + wr * 128 + mh * 64 + f * 16 + kq * 4;
            #pragma unroll
            for (int nh = 0; nh < 2; ++nh)
                #pragma unroll
                for (int jj = 0; jj < 2; ++jj) {
                    int l_ = nB0 + wc * 64 + (nh * 2 + jj) * 16 + rm;
                    f32x4 v = acc[mh * 4 + f][nh * 2 + jj];
                    #pragma unroll
                    for (int r = 0; r < 4; ++r)
                        Co[(size_t)(k_ + r) * NPIX + l_] = v[r] * 1.0e-3f;
                }
        }
}

extern "C" void kernel_launch(void* const* d_in, const int* in_sizes, int n_in,
                              void* d_out, int out_size, void* d_ws, size_t ws_size,
                              hipStream_t stream) {
    const float* img = (const float*)d_in[0];
    float* out = (float*)d_out;

    unsigned short* D  = (unsigned short*)d_ws;                       // 512 KB
    unsigned short* sT = (unsigned short*)((char*)d_ws + 512 * 1024); // 48 MB

    k_basis<<<dim3(512 * 512 / 256), dim3(256), 0, stream>>>(D);

    // Stage 1 (R14-best: 16 single-barrier phases, fused fp32 staging): sT[l][h]
    k_s1x<<<dim3(NWG13), dim3(512), 0, stream>>>(D, img, sT);

    // Stage 2: out[k][l] = (D @ sT^T)[k][l] * 1e-3
    k_s2g<<<dim3(NWG8), dim3(512), 0, stream>>>(D, sT, out);
}